// Round 1
// baseline (336.440 us; speedup 1.0000x reference)
//
#include <hip/hip_runtime.h>
#include <cstdint>
#include <cstddef>

// Problem constants
#define Bb   64
#define Ll   2048
#define Mm   128
#define ROWS (Bb * Ll)          // 131072
#define OUTC 768                // 6*M
#define LDA  136                // padded LDS row stride (bf16 elems): 272B -> bank-balanced

typedef __attribute__((ext_vector_type(4))) float  f32x4;
typedef __attribute__((ext_vector_type(8))) short  bf16x8;   // storage for 8 bf16
typedef __attribute__((ext_vector_type(4))) short  short4v;
typedef __bf16 bf16x8b __attribute__((ext_vector_type(8)));  // builtin operand type

__device__ __forceinline__ float rcp_(float x) {
#if __has_builtin(__builtin_amdgcn_rcpf)
    return __builtin_amdgcn_rcpf(x);
#else
    return 1.0f / x;
#endif
}
__device__ __forceinline__ float sigmoid_(float x) {
    return rcp_(1.0f + __expf(-x));
}
__device__ __forceinline__ float tanh_(float x) {
    float ax = fabsf(x);
    float r  = __expf(-2.0f * ax);
    float t  = (1.0f - r) * rcp_(1.0f + r);
    return x < 0.0f ? -t : t;
}
// f32 -> bf16 bits, round-to-nearest-even
__device__ __forceinline__ short f2bf(float f) {
    uint32_t u = __builtin_bit_cast(uint32_t, f);
    u = (u + 0x7FFFu + ((u >> 16) & 1u)) >> 16;
    return (short)(u & 0xFFFFu);
}

// ---------------------------------------------------------------------------
// Kernel 1: collapsed tree state. The composer input is the same for every
// position at a level, so the whole tree is one (B,M) state iterated depth-1
// times. Then apply leaf() to final h and c states.
// ws layout: [0]=cph, [1]=cpc, [2]=hph, [3]=hpc, each (64,128) f32.
// ---------------------------------------------------------------------------
__global__ __launch_bounds__(128)
void state_kernel(const float* __restrict__ root_c, const float* __restrict__ root_h,
                  const float* __restrict__ Wi, const float* __restrict__ bi,
                  const float* __restrict__ Wf, const float* __restrict__ bfv,
                  const float* __restrict__ Wu, const float* __restrict__ bu,
                  const float* __restrict__ Wc, const float* __restrict__ bc,
                  const float* __restrict__ Wo, const float* __restrict__ bo,
                  float* __restrict__ ws)
{
    const int b = blockIdx.x;
    const int m = threadIdx.x;
    __shared__ float h_sh[Mm];
    __shared__ float c_sh[Mm];

    float c = root_c[b * Mm + m];
    h_sh[m] = root_h[b * Mm + m];
    __syncthreads();

    const float bi_m = bi[m], bf_m = bfv[m], bu_m = bu[m];

    for (int it = 0; it < 10; ++it) {          // depth-1 = log2(2048)-1 = 10
        float di = 0.f, df = 0.f, du = 0.f;
        #pragma unroll 16
        for (int k = 0; k < Mm; ++k) {
            float hk = h_sh[k];
            di = fmaf(hk, Wi[k * Mm + m], di);
            df = fmaf(hk, Wf[k * Mm + m], df);
            du = fmaf(hk, Wu[k * Mm + m], du);
        }
        float ig = sigmoid_(di + bi_m);
        float fg = sigmoid_(df + bf_m);
        float ug = tanh_(du + bu_m);
        c = ig * ug + fg * c;
        __syncthreads();                        // all reads of h_sh done
        h_sh[m] = tanh_(c);
        __syncthreads();
    }

    c_sh[m] = c;
    __syncthreads();

    // leaf(h_state) -> cph,hph ; leaf(c_state) -> cpc,hpc
    float dch = 0.f, doh = 0.f, dcc = 0.f, doc = 0.f;
    #pragma unroll 8
    for (int k = 0; k < Mm; ++k) {
        float hk = h_sh[k], ck = c_sh[k];
        float wc = Wc[k * Mm + m], wo = Wo[k * Mm + m];
        dch = fmaf(hk, wc, dch);
        doh = fmaf(hk, wo, doh);
        dcc = fmaf(ck, wc, dcc);
        doc = fmaf(ck, wo, doc);
    }
    const float bcm = bc[m], bom = bo[m];
    float cph = dch + bcm;
    float cpc = dcc + bcm;
    float hph = sigmoid_(doh + bom) * tanh_(cph);
    float hpc = sigmoid_(doc + bom) * tanh_(cpc);

    ws[0 * Bb * Mm + b * Mm + m] = cph;
    ws[1 * Bb * Mm + b * Mm + m] = cpc;
    ws[2 * Bb * Mm + b * Mm + m] = hph;
    ws[3 * Bb * Mm + b * Mm + m] = hpc;
}

// ---------------------------------------------------------------------------
// Kernel 2: leaf(embs) via bf16 MFMA + full output assembly (fused broadcast).
// Block = 256 thr (4 waves). Block tile = 64 rows x 256 cols (c|o).
// Wave w owns cols [32w,32w+32) of BOTH Wc and Wo so h=sig(o)*tanh(c) is local.
// W fragments live in registers (loaded once); A staged bf16 in LDS per tile.
// ---------------------------------------------------------------------------
__global__ __launch_bounds__(256, 2)
void leaf_kernel(const float* __restrict__ embs,
                 const float* __restrict__ Wc, const float* __restrict__ bc,
                 const float* __restrict__ Wo, const float* __restrict__ bo,
                 const float* __restrict__ state,
                 float* __restrict__ out)
{
    __shared__ short A_sh[64 * LDA];

    const int tid  = threadIdx.x;
    const int w    = tid >> 6;          // wave 0..3
    const int lane = tid & 63;
    const int g    = lane >> 4;         // lane group 0..3
    const int ln   = lane & 15;
    const int n0   = w * 32 + ln;       // base output col (t adds 16)

    // --- preload B fragments (registers, reused for all tiles) -------------
    // k-slot convention: k = ks*32 + g*8 + j  (consistent A/B => permutation
    // over k cancels regardless of HW sub-layout of the K=32 dimension)
    bf16x8 bfrag[2][2][4];              // [t][gate][ks]
    #pragma unroll
    for (int t = 0; t < 2; ++t) {
        #pragma unroll
        for (int gate = 0; gate < 2; ++gate) {
            const float* W = gate ? Wo : Wc;
            #pragma unroll
            for (int ks = 0; ks < 4; ++ks) {
                bf16x8 f;
                #pragma unroll
                for (int j = 0; j < 8; ++j)
                    f[j] = f2bf(W[(ks * 32 + g * 8 + j) * Mm + n0 + t * 16]);
                bfrag[t][gate][ks] = f;
            }
        }
    }
    float biasc[2], biaso[2];
    #pragma unroll
    for (int t = 0; t < 2; ++t) {
        biasc[t] = bc[n0 + t * 16];
        biaso[t] = bo[n0 + t * 16];
    }

    for (int tile = blockIdx.x; tile < ROWS / 64; tile += gridDim.x) {
        const int rowbase = tile * 64;
        const int b = rowbase >> 11;    // rowbase / 2048 (tile never spans b)

        // broadcast state values for this b (cph,cpc,hph,hpc at my cols)
        float sv[4][2];
        #pragma unroll
        for (int s = 0; s < 4; ++s)
            #pragma unroll
            for (int t = 0; t < 2; ++t)
                sv[s][t] = state[s * Bb * Mm + b * Mm + n0 + t * 16];

        // --- stage A tile: 64 rows x 128 k, f32 -> bf16 -> LDS -------------
        #pragma unroll
        for (int i = 0; i < 8; ++i) {
            int idx = tid + 256 * i;            // 0..2047 float4s
            int r   = idx >> 5;                 // 32 float4 per row
            int kq  = idx & 31;
            f32x4 v = *(const f32x4*)(embs + (size_t)(rowbase + r) * Mm + kq * 4);
            short4v s4;
            s4[0] = f2bf(v[0]); s4[1] = f2bf(v[1]);
            s4[2] = f2bf(v[2]); s4[3] = f2bf(v[3]);
            *(short4v*)(&A_sh[r * LDA + kq * 4]) = s4;
        }
        __syncthreads();

        // --- MFMA: 4 row-subtiles x {2 coltiles x 2 gates} x 4 k-steps -----
        f32x4 acc[4][2][2];                     // [rt][t][gate], bias-initialized
        #pragma unroll
        for (int rt = 0; rt < 4; ++rt)
            #pragma unroll
            for (int t = 0; t < 2; ++t)
                #pragma unroll
                for (int gate = 0; gate < 2; ++gate) {
                    float bv = gate ? biaso[t] : biasc[t];
                    acc[rt][t][gate][0] = bv; acc[rt][t][gate][1] = bv;
                    acc[rt][t][gate][2] = bv; acc[rt][t][gate][3] = bv;
                }

        #pragma unroll
        for (int ks = 0; ks < 4; ++ks) {
            bf16x8 af[4];
            #pragma unroll
            for (int rt = 0; rt < 4; ++rt)
                af[rt] = *(const bf16x8*)(&A_sh[(rt * 16 + ln) * LDA + ks * 32 + g * 8]);
            #pragma unroll
            for (int rt = 0; rt < 4; ++rt)
                #pragma unroll
                for (int t = 0; t < 2; ++t)
                    #pragma unroll
                    for (int gate = 0; gate < 2; ++gate)
                        acc[rt][t][gate] = __builtin_amdgcn_mfma_f32_16x16x32_bf16(
                            __builtin_bit_cast(bf16x8b, af[rt]),
                            __builtin_bit_cast(bf16x8b, bfrag[t][gate][ks]),
                            acc[rt][t][gate], 0, 0, 0);
        }
        __syncthreads();   // LDS reads done before next tile's staging

        // --- epilogue: activations + full 768-col row assembly -------------
        // D layout (verified): col = lane&15, row = 4*(lane>>4) + reg
        #pragma unroll
        for (int rt = 0; rt < 4; ++rt) {
            #pragma unroll
            for (int t = 0; t < 2; ++t) {
                f32x4 cf = acc[rt][t][0];
                f32x4 of = acc[rt][t][1];
                int n = n0 + t * 16;
                #pragma unroll
                for (int r = 0; r < 4; ++r) {
                    int row  = rowbase + rt * 16 + g * 4 + r;
                    float cv = cf[r];
                    float hv = sigmoid_(of[r]) * tanh_(cv);
                    float* orow = out + (size_t)row * OUTC;
                    orow[n]       = cv;         // ce
                    orow[128 + n] = sv[0][t];   // cph
                    orow[256 + n] = sv[1][t];   // cpc
                    orow[384 + n] = hv;         // he
                    orow[512 + n] = sv[2][t];   // hph
                    orow[640 + n] = sv[3][t];   // hpc
                }
            }
        }
    }
}

extern "C" void kernel_launch(void* const* d_in, const int* in_sizes, int n_in,
                              void* d_out, int out_size, void* d_ws, size_t ws_size,
                              hipStream_t stream) {
    const float* embs   = (const float*)d_in[0];
    const float* root_c = (const float*)d_in[1];
    const float* root_h = (const float*)d_in[2];
    const float* Wi = (const float*)d_in[3];
    const float* bi = (const float*)d_in[4];
    const float* Wf = (const float*)d_in[5];
    const float* bfv= (const float*)d_in[6];
    const float* Wu = (const float*)d_in[7];
    const float* bu = (const float*)d_in[8];
    const float* Wc = (const float*)d_in[9];
    const float* bc = (const float*)d_in[10];
    const float* Wo = (const float*)d_in[11];
    const float* bo = (const float*)d_in[12];

    float* out   = (float*)d_out;
    float* state = (float*)d_ws;   // 4 * 64 * 128 f32 = 128 KB

    state_kernel<<<dim3(Bb), dim3(Mm), 0, stream>>>(
        root_c, root_h, Wi, bi, Wf, bfv, Wu, bu, Wc, bc, Wo, bo, state);
    leaf_kernel<<<dim3(512), dim3(256), 0, stream>>>(
        embs, Wc, bc, Wo, bo, state, out);
}

// Round 2
// 289.351 us; speedup vs baseline: 1.1627x; 1.1627x over previous
//
#include <hip/hip_runtime.h>
#include <cstdint>
#include <cstddef>

// Problem constants
#define Bb   64
#define Ll   2048
#define Mm   128
#define ROWS (Bb * Ll)          // 131072
#define OUTC 768                // 6*M
#define LDA  136                // padded LDS row stride (bf16 elems)

typedef __attribute__((ext_vector_type(4))) float  f32x4;
typedef __attribute__((ext_vector_type(8))) short  bf16x8;   // storage for 8 bf16
typedef __attribute__((ext_vector_type(4))) short  short4v;
typedef __bf16 bf16x8b __attribute__((ext_vector_type(8)));  // builtin operand type

__device__ __forceinline__ float rcp_(float x) {
#if __has_builtin(__builtin_amdgcn_rcpf)
    return __builtin_amdgcn_rcpf(x);
#else
    return 1.0f / x;
#endif
}
__device__ __forceinline__ float sigmoid_(float x) {
    return rcp_(1.0f + __expf(-x));
}
__device__ __forceinline__ float tanh_(float x) {
    float ax = fabsf(x);
    float r  = __expf(-2.0f * ax);
    float t  = (1.0f - r) * rcp_(1.0f + r);
    return x < 0.0f ? -t : t;
}
// f32 -> bf16 bits, round-to-nearest-even
__device__ __forceinline__ short f2bf(float f) {
    uint32_t u = __builtin_bit_cast(uint32_t, f);
    u = (u + 0x7FFFu + ((u >> 16) & 1u)) >> 16;
    return (short)(u & 0xFFFFu);
}

// ---------------------------------------------------------------------------
// ws layout (floats):
//   [0 .. 32768)   : state: [0]=cph, [1]=cpc, [2]=hph, [3]=hpc, each (64,128)
//   [32768 .. )    : Wbf (as shorts at (short*)ws + 65536):
//                    [gate][col][k] bf16, gate 0=Wc 1=Wo, 2*128*128 shorts
// ---------------------------------------------------------------------------

// Kernel 1: collapsed tree state (tree children are identical => one (B,M)
// state iterated depth-1 times), then leaf() on final h and c states.
__global__ __launch_bounds__(128)
void state_kernel(const float* __restrict__ root_c, const float* __restrict__ root_h,
                  const float* __restrict__ Wi, const float* __restrict__ bi,
                  const float* __restrict__ Wf, const float* __restrict__ bfv,
                  const float* __restrict__ Wu, const float* __restrict__ bu,
                  const float* __restrict__ Wc, const float* __restrict__ bc,
                  const float* __restrict__ Wo, const float* __restrict__ bo,
                  float* __restrict__ ws)
{
    const int b = blockIdx.x;
    const int m = threadIdx.x;
    __shared__ float h_sh[Mm];
    __shared__ float c_sh[Mm];

    float c = root_c[b * Mm + m];
    h_sh[m] = root_h[b * Mm + m];
    __syncthreads();

    const float bi_m = bi[m], bf_m = bfv[m], bu_m = bu[m];

    for (int it = 0; it < 10; ++it) {          // depth-1 = log2(2048)-1 = 10
        float di = 0.f, df = 0.f, du = 0.f;
        #pragma unroll 16
        for (int k = 0; k < Mm; ++k) {
            float hk = h_sh[k];
            di = fmaf(hk, Wi[k * Mm + m], di);
            df = fmaf(hk, Wf[k * Mm + m], df);
            du = fmaf(hk, Wu[k * Mm + m], du);
        }
        float ig = sigmoid_(di + bi_m);
        float fg = sigmoid_(df + bf_m);
        float ug = tanh_(du + bu_m);
        c = ig * ug + fg * c;
        __syncthreads();
        h_sh[m] = tanh_(c);
        __syncthreads();
    }

    c_sh[m] = c;
    __syncthreads();

    float dch = 0.f, doh = 0.f, dcc = 0.f, doc = 0.f;
    #pragma unroll 8
    for (int k = 0; k < Mm; ++k) {
        float hk = h_sh[k], ck = c_sh[k];
        float wc = Wc[k * Mm + m], wo = Wo[k * Mm + m];
        dch = fmaf(hk, wc, dch);
        doh = fmaf(hk, wo, doh);
        dcc = fmaf(ck, wc, dcc);
        doc = fmaf(ck, wo, doc);
    }
    const float bcm = bc[m], bom = bo[m];
    float cph = dch + bcm;
    float cpc = dcc + bcm;
    float hph = sigmoid_(doh + bom) * tanh_(cph);
    float hpc = sigmoid_(doc + bom) * tanh_(cpc);

    ws[0 * Bb * Mm + b * Mm + m] = cph;
    ws[1 * Bb * Mm + b * Mm + m] = cpc;
    ws[2 * Bb * Mm + b * Mm + m] = hph;
    ws[3 * Bb * Mm + b * Mm + m] = hpc;
}

// Kernel 2: convert Wc/Wo to bf16, transposed to [gate][col][k] so leaf's
// B-fragments are single 16B loads.
__global__ __launch_bounds__(256)
void wprep_kernel(const float* __restrict__ Wc, const float* __restrict__ Wo,
                  short* __restrict__ wbf)
{
    int idx  = blockIdx.x * 256 + threadIdx.x;   // 0..32767
    int gate = idx >> 14;
    int rest = idx & 16383;
    int col  = rest >> 7;
    int k    = rest & 127;
    const float* W = gate ? Wo : Wc;
    wbf[idx] = f2bf(W[k * Mm + col]);
}

// Kernel 3: broadcast sections. out[row][128..384)=cph|cpc, [512..768)=hph|hpc
// per batch b — pure coalesced f32x4 stores (268 MB of the 402 MB output).
__global__ __launch_bounds__(256)
void bcast_kernel(const float* __restrict__ state, float* __restrict__ out)
{
    const int tid     = threadIdx.x;
    const int rowbase = blockIdx.x * 64;       // 2048 blocks
    const int b       = rowbase >> 11;

    const int slot = tid & 127;                // f32x4 slot within row's bcast cols
    const int part = slot >> 6;                // 0 = c sections, 1 = h sections
    const int q    = slot & 63;                // 0..63 across the two 128-col sections
    const int s    = part * 2 + (q >> 5);      // cph,cpc,hph,hpc
    const int qq   = q & 31;

    f32x4 v = *(const f32x4*)(state + s * Bb * Mm + b * Mm + qq * 4);

    const int colb = 128 + part * 384 + q * 4;
    const int r0   = rowbase + (tid >> 7);

    #pragma unroll 8
    for (int i = 0; i < 32; ++i) {
        int row = r0 + 2 * i;
        __builtin_nontemporal_store(v, (f32x4*)(out + (size_t)row * OUTC + colb));
    }
}

// Kernel 4: leaf(embs) via bf16 MFMA; writes ce ([0..128)) and he ([384..512)).
// One 64-row tile per block; 2048 blocks x 256 thr (4 waves).
// Wave w owns cols [32w,32w+32) of both gates.
__global__ __launch_bounds__(256, 2)
void leaf_kernel(const float* __restrict__ embs,
                 const short* __restrict__ wbf,
                 const float* __restrict__ bc, const float* __restrict__ bo,
                 float* __restrict__ out)
{
    __shared__ short A_sh[64 * LDA];

    const int tid  = threadIdx.x;
    const int w    = tid >> 6;          // wave 0..3
    const int lane = tid & 63;
    const int g    = lane >> 4;         // lane group 0..3
    const int ln   = lane & 15;
    const int n0   = w * 32 + ln;       // base output col (t adds 16)
    const int rowbase = blockIdx.x * 64;

    // --- B fragments: 16 x 16B vector loads (pre-transposed bf16) ----------
    // k-enumeration: k = ks*32 + g*8 + j, consistent with A reads below.
    bf16x8 bfrag[2][2][4];              // [t][gate][ks]
    #pragma unroll
    for (int t = 0; t < 2; ++t)
        #pragma unroll
        for (int gate = 0; gate < 2; ++gate)
            #pragma unroll
            for (int ks = 0; ks < 4; ++ks)
                bfrag[t][gate][ks] = *(const bf16x8*)(
                    wbf + gate * (Mm * Mm) + (n0 + t * 16) * Mm + ks * 32 + g * 8);

    float biasc[2], biaso[2];
    #pragma unroll
    for (int t = 0; t < 2; ++t) {
        biasc[t] = bc[n0 + t * 16];
        biaso[t] = bo[n0 + t * 16];
    }

    // --- stage A tile: 64 rows x 128 k, f32 -> bf16 -> LDS -----------------
    #pragma unroll
    for (int i = 0; i < 8; ++i) {
        int idx = tid + 256 * i;            // 0..2047 float4-slots
        int r   = idx >> 5;                 // 32 float4 per row
        int kq  = idx & 31;
        f32x4 v = *(const f32x4*)(embs + (size_t)(rowbase + r) * Mm + kq * 4);
        short4v s4;
        s4[0] = f2bf(v[0]); s4[1] = f2bf(v[1]);
        s4[2] = f2bf(v[2]); s4[3] = f2bf(v[3]);
        *(short4v*)(&A_sh[r * LDA + kq * 4]) = s4;
    }
    __syncthreads();

    // --- MFMA ---------------------------------------------------------------
    f32x4 acc[4][2][2];                     // [rt][t][gate], bias-initialized
    #pragma unroll
    for (int rt = 0; rt < 4; ++rt)
        #pragma unroll
        for (int t = 0; t < 2; ++t)
            #pragma unroll
            for (int gate = 0; gate < 2; ++gate) {
                float bv = gate ? biaso[t] : biasc[t];
                acc[rt][t][gate][0] = bv; acc[rt][t][gate][1] = bv;
                acc[rt][t][gate][2] = bv; acc[rt][t][gate][3] = bv;
            }

    #pragma unroll
    for (int ks = 0; ks < 4; ++ks) {
        bf16x8 af[4];
        #pragma unroll
        for (int rt = 0; rt < 4; ++rt)
            af[rt] = *(const bf16x8*)(&A_sh[(rt * 16 + ln) * LDA + ks * 32 + g * 8]);
        #pragma unroll
        for (int rt = 0; rt < 4; ++rt)
            #pragma unroll
            for (int t = 0; t < 2; ++t)
                #pragma unroll
                for (int gate = 0; gate < 2; ++gate)
                    acc[rt][t][gate] = __builtin_amdgcn_mfma_f32_16x16x32_bf16(
                        __builtin_bit_cast(bf16x8b, af[rt]),
                        __builtin_bit_cast(bf16x8b, bfrag[t][gate][ks]),
                        acc[rt][t][gate], 0, 0, 0);
    }

    // --- epilogue: activations + ce/he stores -------------------------------
    // D layout (verified): col = lane&15, row = 4*(lane>>4) + reg
    #pragma unroll
    for (int rt = 0; rt < 4; ++rt) {
        #pragma unroll
        for (int t = 0; t < 2; ++t) {
            f32x4 cf = acc[rt][t][0];
            f32x4 of = acc[rt][t][1];
            int n = n0 + t * 16;
            #pragma unroll
            for (int r = 0; r < 4; ++r) {
                int row  = rowbase + rt * 16 + g * 4 + r;
                float cv = cf[r];
                float hv = sigmoid_(of[r]) * tanh_(cv);
                float* orow = out + (size_t)row * OUTC;
                orow[n]       = cv;         // ce
                orow[384 + n] = hv;         // he
            }
        }
    }
}

extern "C" void kernel_launch(void* const* d_in, const int* in_sizes, int n_in,
                              void* d_out, int out_size, void* d_ws, size_t ws_size,
                              hipStream_t stream) {
    const float* embs   = (const float*)d_in[0];
    const float* root_c = (const float*)d_in[1];
    const float* root_h = (const float*)d_in[2];
    const float* Wi = (const float*)d_in[3];
    const float* bi = (const float*)d_in[4];
    const float* Wf = (const float*)d_in[5];
    const float* bfv= (const float*)d_in[6];
    const float* Wu = (const float*)d_in[7];
    const float* bu = (const float*)d_in[8];
    const float* Wc = (const float*)d_in[9];
    const float* bc = (const float*)d_in[10];
    const float* Wo = (const float*)d_in[11];
    const float* bo = (const float*)d_in[12];

    float* out   = (float*)d_out;
    float* state = (float*)d_ws;                       // 128 KB
    short* wbf   = (short*)d_ws + 65536;               // 64 KB bf16 W

    state_kernel<<<dim3(Bb), dim3(Mm), 0, stream>>>(
        root_c, root_h, Wi, bi, Wf, bfv, Wu, bu, Wc, bc, Wo, bo, state);
    wprep_kernel<<<dim3(128), dim3(256), 0, stream>>>(Wc, Wo, wbf);
    bcast_kernel<<<dim3(2048), dim3(256), 0, stream>>>(state, out);
    leaf_kernel<<<dim3(2048), dim3(256), 0, stream>>>(embs, wbf, bc, bo, out);
}

// Round 3
// 132.400 us; speedup vs baseline: 2.5411x; 2.1854x over previous
//
#include <hip/hip_runtime.h>
#include <cstdint>
#include <cstddef>

// Problem constants
#define Bb   64
#define Ll   2048
#define Mm   128
#define ROWS (Bb * Ll)          // 131072
#define OUTC 768                // 6*M
#define LDA  136                // A-stage LDS stride (bf16 elems)
#define LDF  132                // epilogue LDS stride (f32 elems)

typedef __attribute__((ext_vector_type(4))) float  f32x4;
typedef __attribute__((ext_vector_type(8))) short  bf16x8;   // storage for 8 bf16
typedef __attribute__((ext_vector_type(4))) short  short4v;
typedef __bf16 bf16x8b __attribute__((ext_vector_type(8)));  // builtin operand type

__device__ __forceinline__ float rcp_(float x) {
#if __has_builtin(__builtin_amdgcn_rcpf)
    return __builtin_amdgcn_rcpf(x);
#else
    return 1.0f / x;
#endif
}
__device__ __forceinline__ float sigmoid_(float x) {
    return rcp_(1.0f + __expf(-x));
}
__device__ __forceinline__ float tanh_(float x) {
    float ax = fabsf(x);
    float r  = __expf(-2.0f * ax);
    float t  = (1.0f - r) * rcp_(1.0f + r);
    return x < 0.0f ? -t : t;
}
// f32 -> bf16 bits, round-to-nearest-even
__device__ __forceinline__ short f2bf(float f) {
    uint32_t u = __builtin_bit_cast(uint32_t, f);
    u = (u + 0x7FFFu + ((u >> 16) & 1u)) >> 16;
    return (short)(u & 0xFFFFu);
}

// ---------------------------------------------------------------------------
// ws layout:
//   floats [0 .. 32768)          : state: [0]=cph,[1]=cpc,[2]=hph,[3]=hpc (64,128)
//   shorts [65536 .. 98304)      : Wbf [gate][col][k] bf16, gate 0=Wc 1=Wo
// ---------------------------------------------------------------------------

// Kernel 1: collapsed tree state (both children identical => one (B,M) state
// iterated depth-1 times), then leaf() on final h and c. Also converts Wc/Wo
// to transposed bf16 (fused wprep; independent work, no sync needed).
__global__ __launch_bounds__(128)
void state_kernel(const float* __restrict__ root_c, const float* __restrict__ root_h,
                  const float* __restrict__ Wi, const float* __restrict__ bi,
                  const float* __restrict__ Wf, const float* __restrict__ bfv,
                  const float* __restrict__ Wu, const float* __restrict__ bu,
                  const float* __restrict__ Wc, const float* __restrict__ bc,
                  const float* __restrict__ Wo, const float* __restrict__ bo,
                  float* __restrict__ ws, short* __restrict__ wbf)
{
    const int b = blockIdx.x;
    const int m = threadIdx.x;
    __shared__ float h_sh[Mm];
    __shared__ float c_sh[Mm];

    // fused wprep: 64*128 = 8192 threads, 4 elements each (writes coalesced)
    {
        int gtid = b * 128 + m;
        #pragma unroll
        for (int j = 0; j < 4; ++j) {
            int idx  = gtid + 8192 * j;          // 0..32767
            int gate = idx >> 14;
            int col  = (idx >> 7) & 127;
            int k    = idx & 127;
            const float* W = gate ? Wo : Wc;
            wbf[idx] = f2bf(W[k * Mm + col]);
        }
    }

    float c = root_c[b * Mm + m];
    h_sh[m] = root_h[b * Mm + m];
    __syncthreads();

    const float bi_m = bi[m], bf_m = bfv[m], bu_m = bu[m];

    for (int it = 0; it < 10; ++it) {          // depth-1 = log2(2048)-1 = 10
        // split accumulators to halve the serial fmaf chain
        float di0 = 0.f, df0 = 0.f, du0 = 0.f;
        float di1 = 0.f, df1 = 0.f, du1 = 0.f;
        #pragma unroll 8
        for (int k = 0; k < Mm; k += 2) {
            float h0 = h_sh[k], h1 = h_sh[k + 1];
            di0 = fmaf(h0, Wi[k * Mm + m], di0);
            di1 = fmaf(h1, Wi[(k + 1) * Mm + m], di1);
            df0 = fmaf(h0, Wf[k * Mm + m], df0);
            df1 = fmaf(h1, Wf[(k + 1) * Mm + m], df1);
            du0 = fmaf(h0, Wu[k * Mm + m], du0);
            du1 = fmaf(h1, Wu[(k + 1) * Mm + m], du1);
        }
        float ig = sigmoid_(di0 + di1 + bi_m);
        float fg = sigmoid_(df0 + df1 + bf_m);
        float ug = tanh_(du0 + du1 + bu_m);
        c = ig * ug + fg * c;
        __syncthreads();
        h_sh[m] = tanh_(c);
        __syncthreads();
    }

    c_sh[m] = c;
    __syncthreads();

    float dch = 0.f, doh = 0.f, dcc = 0.f, doc = 0.f;
    #pragma unroll 8
    for (int k = 0; k < Mm; ++k) {
        float hk = h_sh[k], ck = c_sh[k];
        float wc = Wc[k * Mm + m], wo = Wo[k * Mm + m];
        dch = fmaf(hk, wc, dch);
        doh = fmaf(hk, wo, doh);
        dcc = fmaf(ck, wc, dcc);
        doc = fmaf(ck, wo, doc);
    }
    const float bcm = bc[m], bom = bo[m];
    float cph = dch + bcm;
    float cpc = dcc + bcm;
    float hph = sigmoid_(doh + bom) * tanh_(cph);
    float hpc = sigmoid_(doc + bom) * tanh_(cpc);

    ws[0 * Bb * Mm + b * Mm + m] = cph;
    ws[1 * Bb * Mm + b * Mm + m] = cpc;
    ws[2 * Bb * Mm + b * Mm + m] = hph;
    ws[3 * Bb * Mm + b * Mm + m] = hpc;
}

// ---------------------------------------------------------------------------
// Kernel 2: fused leaf(embs) MFMA + single-pass full-row output assembly.
// 2048 blocks x 512 thr (8 waves). Block = 64 rows; wave w owns output cols
// [16w,16w+16) for BOTH gates. After MFMA, ce/he are transposed through LDS
// (32-row halves) and each 3KB output row is emitted as 192 contiguous f32x4
// stores (1KB per wave-instruction), including the 4 broadcast state sections.
// ---------------------------------------------------------------------------
__global__ __launch_bounds__(512, 4)
void fused_kernel(const float* __restrict__ embs,
                  const short* __restrict__ wbf,
                  const float* __restrict__ bc, const float* __restrict__ bo,
                  const float* __restrict__ state,
                  float* __restrict__ out)
{
    // union'd LDS: A-stage (17408B) dies at the post-MFMA barrier, then the
    // region is reused for ce/he 32-row transpose buffers. state stash is
    // disjoint and persistent.
    __shared__ __align__(16) char smem[35840];
    short* A_sh = (short*)smem;                    // [64][LDA] bf16
    float* ce_l = (float*)smem;                    // [32][LDF] f32
    float* he_l = (float*)(smem + 16896);          // [32][LDF] f32
    float* st_l = (float*)(smem + 33792);          // [4][128]  f32

    const int tid  = threadIdx.x;
    const int w    = tid >> 6;          // wave 0..7
    const int lane = tid & 63;
    const int g    = lane >> 4;         // lane group 0..3 (k-chunk / row sub)
    const int ln   = lane & 15;
    const int n0   = w * 16 + ln;       // output col 0..127
    const int rowbase = blockIdx.x * 64;
    const int b       = rowbase >> 11;

    // --- B fragments early (global loads fly during staging) ---------------
    // k-enumeration: k = ks*32 + g*8 + j, consistent with A reads below.
    bf16x8 bfrag[2][4];                 // [gate][ks]
    #pragma unroll
    for (int gate = 0; gate < 2; ++gate)
        #pragma unroll
        for (int ks = 0; ks < 4; ++ks)
            bfrag[gate][ks] = *(const bf16x8*)(
                wbf + gate * (Mm * Mm) + n0 * Mm + ks * 32 + g * 8);

    const float biasc = bc[n0];
    const float biaso = bo[n0];

    // --- broadcast state for this batch -> LDS (512 floats, 1 per thread) --
    st_l[tid] = state[(tid >> 7) * (Bb * Mm) + b * Mm + (tid & 127)];

    // --- stage A tile: 64 rows x 128 k, f32 -> bf16 -> LDS ------------------
    #pragma unroll
    for (int i = 0; i < 4; ++i) {
        int idx = tid + 512 * i;            // 0..2047 float4-slots
        int r   = idx >> 5;                 // 32 float4 per row
        int kq  = idx & 31;
        f32x4 v = *(const f32x4*)(embs + (size_t)(rowbase + r) * Mm + kq * 4);
        short4v s4;
        s4[0] = f2bf(v[0]); s4[1] = f2bf(v[1]);
        s4[2] = f2bf(v[2]); s4[3] = f2bf(v[3]);
        *(short4v*)(&A_sh[r * LDA + kq * 4]) = s4;
    }
    __syncthreads();

    // --- MFMA: 4 row-subtiles x 2 gates x 4 k-steps -------------------------
    f32x4 acc[4][2];                        // [rt][gate], bias-initialized
    #pragma unroll
    for (int rt = 0; rt < 4; ++rt)
        #pragma unroll
        for (int gate = 0; gate < 2; ++gate) {
            float bv = gate ? biaso : biasc;
            acc[rt][gate][0] = bv; acc[rt][gate][1] = bv;
            acc[rt][gate][2] = bv; acc[rt][gate][3] = bv;
        }

    #pragma unroll
    for (int ks = 0; ks < 4; ++ks) {
        bf16x8 af[4];
        #pragma unroll
        for (int rt = 0; rt < 4; ++rt)
            af[rt] = *(const bf16x8*)(&A_sh[(rt * 16 + ln) * LDA + ks * 32 + g * 8]);
        #pragma unroll
        for (int rt = 0; rt < 4; ++rt)
            #pragma unroll
            for (int gate = 0; gate < 2; ++gate)
                acc[rt][gate] = __builtin_amdgcn_mfma_f32_16x16x32_bf16(
                    __builtin_bit_cast(bf16x8b, af[rt]),
                    __builtin_bit_cast(bf16x8b, bfrag[gate][ks]),
                    acc[rt][gate], 0, 0, 0);
    }
    __syncthreads();    // A_sh fully consumed; region reusable

    // --- epilogue: two 32-row halves, LDS transpose, wide row stores --------
    // D layout (verified): col = lane&15 (= our n0), row = 4*(lane>>4) + reg
    #pragma unroll
    for (int half = 0; half < 2; ++half) {
        #pragma unroll
        for (int q = 0; q < 2; ++q) {
            int rt = half * 2 + q;
            #pragma unroll
            for (int r = 0; r < 4; ++r) {
                int rowL = q * 16 + g * 4 + r;          // 0..31 in this half
                float cv = acc[rt][0][r];
                float hv = sigmoid_(acc[rt][1][r]) * tanh_(cv);
                ce_l[rowL * LDF + n0] = cv;
                he_l[rowL * LDF + n0] = hv;
            }
        }
        __syncthreads();

        // 32 rows x 192 f32x4 = 6144 units; 12 per thread; lanes contiguous
        #pragma unroll
        for (int i = 0; i < 12; ++i) {
            int u  = tid + 512 * i;
            int rg = u / 192;
            int s  = u - rg * 192;          // f32x4 col within row, 0..191
            int sec = s >> 5;               // 0:ce 1:cph 2:cpc 3:he 4:hph 5:hpc
            int c   = s & 31;
            const float* src =
                (sec == 0) ? (ce_l + rg * LDF + c * 4) :
                (sec == 3) ? (he_l + rg * LDF + c * 4) :
                (st_l + ((sec < 3) ? (sec - 1) : (sec - 2)) * 128 + c * 4);
            f32x4 v = *(const f32x4*)src;
            *(f32x4*)(out + (size_t)(rowbase + half * 32 + rg) * OUTC + s * 4) = v;
        }
        if (half == 0) __syncthreads();     // reads done before overwrite
    }
}

extern "C" void kernel_launch(void* const* d_in, const int* in_sizes, int n_in,
                              void* d_out, int out_size, void* d_ws, size_t ws_size,
                              hipStream_t stream) {
    const float* embs   = (const float*)d_in[0];
    const float* root_c = (const float*)d_in[1];
    const float* root_h = (const float*)d_in[2];
    const float* Wi = (const float*)d_in[3];
    const float* bi = (const float*)d_in[4];
    const float* Wf = (const float*)d_in[5];
    const float* bfv= (const float*)d_in[6];
    const float* Wu = (const float*)d_in[7];
    const float* bu = (const float*)d_in[8];
    const float* Wc = (const float*)d_in[9];
    const float* bc = (const float*)d_in[10];
    const float* Wo = (const float*)d_in[11];
    const float* bo = (const float*)d_in[12];

    float* out   = (float*)d_out;
    float* state = (float*)d_ws;                       // 128 KB
    short* wbf   = (short*)d_ws + 65536;               // 64 KB bf16 W

    state_kernel<<<dim3(Bb), dim3(Mm), 0, stream>>>(
        root_c, root_h, Wi, bi, Wf, bfv, Wu, bu, Wc, bc, Wo, bo, state, wbf);
    fused_kernel<<<dim3(2048), dim3(512), 0, stream>>>(
        embs, wbf, bc, bo, state, out);
}

// Round 4
// 110.435 us; speedup vs baseline: 3.0465x; 1.1989x over previous
//
#include <hip/hip_runtime.h>
#include <cstdint>
#include <cstddef>

// Problem constants
#define Bb   64
#define Ll   2048
#define Mm   128
#define ROWS (Bb * Ll)          // 131072
#define OUTC 768                // 6*M
#define LDA  136                // A-stage LDS stride (bf16 elems)
#define LDF  132                // epilogue LDS stride (f32 elems)

typedef __attribute__((ext_vector_type(4))) float  f32x4;
typedef __attribute__((ext_vector_type(8))) short  bf16x8;   // storage for 8 bf16
typedef __attribute__((ext_vector_type(4))) short  short4v;
typedef __bf16 bf16x8b __attribute__((ext_vector_type(8)));  // builtin operand type

__device__ __forceinline__ float rcp_(float x) {
#if __has_builtin(__builtin_amdgcn_rcpf)
    return __builtin_amdgcn_rcpf(x);
#else
    return 1.0f / x;
#endif
}
__device__ __forceinline__ float sigmoid_(float x) {
    return rcp_(1.0f + __expf(-x));
}
__device__ __forceinline__ float tanh_(float x) {
    float ax = fabsf(x);
    float r  = __expf(-2.0f * ax);
    float t  = (1.0f - r) * rcp_(1.0f + r);
    return x < 0.0f ? -t : t;
}
// f32 -> bf16 bits, round-to-nearest-even
__device__ __forceinline__ short f2bf(float f) {
    uint32_t u = __builtin_bit_cast(uint32_t, f);
    u = (u + 0x7FFFu + ((u >> 16) & 1u)) >> 16;
    return (short)(u & 0xFFFFu);
}

// ---------------------------------------------------------------------------
// ws layout:
//   floats [0 .. 32768)          : state: [0]=cph,[1]=cpc,[2]=hph,[3]=hpc (64,128)
//   shorts [65536 .. 98304)      : Wbf [gate][col][k] bf16, gate 0=Wc 1=Wo
// ---------------------------------------------------------------------------

// Kernel 1 (v2): collapsed tree state. 512 threads: tid = q*?? no — m = tid&127,
// q = tid>>7 owns k-range [32q,32q+32). Partial dots reduced through LDS; only
// q==0 lane-set runs the (tiny) activation + state update. 8 waves/CU for
// latency hiding (was 2). wprep fused (1 elem/thread).
__global__ __launch_bounds__(512)
void state_kernel(const float* __restrict__ root_c, const float* __restrict__ root_h,
                  const float* __restrict__ Wi, const float* __restrict__ bi,
                  const float* __restrict__ Wf, const float* __restrict__ bfv,
                  const float* __restrict__ Wu, const float* __restrict__ bu,
                  const float* __restrict__ Wc, const float* __restrict__ bc,
                  const float* __restrict__ Wo, const float* __restrict__ bo,
                  float* __restrict__ ws, short* __restrict__ wbf)
{
    const int b   = blockIdx.x;
    const int tid = threadIdx.x;
    const int m   = tid & 127;
    const int q   = tid >> 7;            // 0..3
    const int k0  = q * 32;

    __shared__ float h_sh[Mm];
    __shared__ float c_sh[Mm];
    __shared__ float part[4][4][Mm];     // [slot][q][m]

    // fused wprep: 64 blocks x 512 threads = 32768 elems, 1 per thread
    {
        int idx  = b * 512 + tid;
        int gate = idx >> 14;
        int col  = (idx >> 7) & 127;
        int k    = idx & 127;
        const float* W = gate ? Wo : Wc;
        wbf[idx] = f2bf(W[k * Mm + col]);
    }

    float c = 0.f;
    if (q == 0) {
        c = root_c[b * Mm + m];
        h_sh[m] = root_h[b * Mm + m];
    }
    __syncthreads();

    const float bi_m = bi[m], bf_m = bfv[m], bu_m = bu[m];

    for (int it = 0; it < 10; ++it) {        // depth-1 = 10
        float di0 = 0.f, di1 = 0.f, df0 = 0.f, df1 = 0.f, du0 = 0.f, du1 = 0.f;
        #pragma unroll
        for (int kk = 0; kk < 32; kk += 2) {
            int k = k0 + kk;
            float h0 = h_sh[k], h1 = h_sh[k + 1];
            di0 = fmaf(h0, Wi[k * Mm + m], di0);
            di1 = fmaf(h1, Wi[(k + 1) * Mm + m], di1);
            df0 = fmaf(h0, Wf[k * Mm + m], df0);
            df1 = fmaf(h1, Wf[(k + 1) * Mm + m], df1);
            du0 = fmaf(h0, Wu[k * Mm + m], du0);
            du1 = fmaf(h1, Wu[(k + 1) * Mm + m], du1);
        }
        part[0][q][m] = di0 + di1;
        part[1][q][m] = df0 + df1;
        part[2][q][m] = du0 + du1;
        __syncthreads();
        if (q == 0) {
            float di = (part[0][0][m] + part[0][1][m]) + (part[0][2][m] + part[0][3][m]);
            float df = (part[1][0][m] + part[1][1][m]) + (part[1][2][m] + part[1][3][m]);
            float du = (part[2][0][m] + part[2][1][m]) + (part[2][2][m] + part[2][3][m]);
            float ig = sigmoid_(di + bi_m);
            float fg = sigmoid_(df + bf_m);
            float ug = tanh_(du + bu_m);
            c = ig * ug + fg * c;
            h_sh[m] = tanh_(c);
        }
        __syncthreads();
    }
    if (q == 0) c_sh[m] = c;
    __syncthreads();

    // leaf on final h and c states, k-split
    float dch = 0.f, doh = 0.f, dcc = 0.f, doc = 0.f;
    #pragma unroll
    for (int kk = 0; kk < 32; ++kk) {
        int k = k0 + kk;
        float hk = h_sh[k], ck = c_sh[k];
        float wc = Wc[k * Mm + m], wo = Wo[k * Mm + m];
        dch = fmaf(hk, wc, dch);
        doh = fmaf(hk, wo, doh);
        dcc = fmaf(ck, wc, dcc);
        doc = fmaf(ck, wo, doc);
    }
    part[0][q][m] = dch;
    part[1][q][m] = doh;
    part[2][q][m] = dcc;
    part[3][q][m] = doc;
    __syncthreads();
    if (q == 0) {
        float Dch = (part[0][0][m] + part[0][1][m]) + (part[0][2][m] + part[0][3][m]);
        float Doh = (part[1][0][m] + part[1][1][m]) + (part[1][2][m] + part[1][3][m]);
        float Dcc = (part[2][0][m] + part[2][1][m]) + (part[2][2][m] + part[2][3][m]);
        float Doc = (part[3][0][m] + part[3][1][m]) + (part[3][2][m] + part[3][3][m]);
        const float bcm = bc[m], bom = bo[m];
        float cph = Dch + bcm;
        float cpc = Dcc + bcm;
        float hph = sigmoid_(Doh + bom) * tanh_(cph);
        float hpc = sigmoid_(Doc + bom) * tanh_(cpc);
        ws[0 * Bb * Mm + b * Mm + m] = cph;
        ws[1 * Bb * Mm + b * Mm + m] = cpc;
        ws[2 * Bb * Mm + b * Mm + m] = hph;
        ws[3 * Bb * Mm + b * Mm + m] = hpc;
    }
}

// ---------------------------------------------------------------------------
// Kernel 2 (v2): fused leaf MFMA + single-pass row assembly, SOFTWARE-PIPELINED
// over 2 tiles/block. 1024 blocks x 512 thr. Tile = 64 rows. While tile0 runs
// MFMA+epilogue, tile1's global loads are already in flight (double-buffered
// A in LDS). embs loads are nontemporal (stream-once; keep L2 for writes).
// ---------------------------------------------------------------------------
__global__ __launch_bounds__(512, 4)
void fused_kernel(const float* __restrict__ embs,
                  const short* __restrict__ wbf,
                  const float* __restrict__ bc, const float* __restrict__ bo,
                  const float* __restrict__ state,
                  float* __restrict__ out)
{
    // carve: A0[64][LDA] bf16 | A1[64][LDA] bf16 | ce[32][LDF] f32 |
    //        he[32][LDF] f32 | st[4][128] f32
    __shared__ __align__(16) char smem[70656];
    short* A0   = (short*)smem;                    // 17408 B
    short* A1   = (short*)(smem + 17408);          // 17408 B
    float* ce_l = (float*)(smem + 34816);          // 16896 B
    float* he_l = (float*)(smem + 51712);          // 16896 B
    float* st_l = (float*)(smem + 68608);          // 2048 B

    const int tid  = threadIdx.x;
    const int w    = tid >> 6;          // wave 0..7
    const int lane = tid & 63;
    const int g    = lane >> 4;         // lane group 0..3
    const int ln   = lane & 15;
    const int n0   = w * 16 + ln;       // output col 0..127
    const int rowbase0 = blockIdx.x * 128;
    const int rowbase1 = rowbase0 + 64;
    const int b        = rowbase0 >> 11;   // 128 | 2048, never spans batches

    // --- B fragments + biases + state stash (fly during staging) -----------
    bf16x8 bfrag[2][4];                 // [gate][ks], k = ks*32 + g*8 + j
    #pragma unroll
    for (int gate = 0; gate < 2; ++gate)
        #pragma unroll
        for (int ks = 0; ks < 4; ++ks)
            bfrag[gate][ks] = *(const bf16x8*)(
                wbf + gate * (Mm * Mm) + n0 * Mm + ks * 32 + g * 8);
    const float biasc = bc[n0];
    const float biaso = bo[n0];
    st_l[tid] = state[(tid >> 7) * (Bb * Mm) + b * Mm + (tid & 127)];

    // helpers ---------------------------------------------------------------
    auto stage_load = [&](int rowbase, f32x4 (&r)[4]) {
        #pragma unroll
        for (int i = 0; i < 4; ++i) {
            int idx = tid + 512 * i;            // 0..2047 float4-slots
            int rr  = idx >> 5;
            int kq  = idx & 31;
            r[i] = __builtin_nontemporal_load(
                (const f32x4*)(embs + (size_t)(rowbase + rr) * Mm + kq * 4));
        }
    };
    auto stage_write = [&](short* A, const f32x4 (&r)[4]) {
        #pragma unroll
        for (int i = 0; i < 4; ++i) {
            int idx = tid + 512 * i;
            int rr  = idx >> 5;
            int kq  = idx & 31;
            short4v s4;
            s4[0] = f2bf(r[i][0]); s4[1] = f2bf(r[i][1]);
            s4[2] = f2bf(r[i][2]); s4[3] = f2bf(r[i][3]);
            *(short4v*)(&A[rr * LDA + kq * 4]) = s4;
        }
    };
    auto do_mfma = [&](const short* A, f32x4 (&acc)[4][2]) {
        #pragma unroll
        for (int rt = 0; rt < 4; ++rt)
            #pragma unroll
            for (int gate = 0; gate < 2; ++gate) {
                float bv = gate ? biaso : biasc;
                acc[rt][gate][0] = bv; acc[rt][gate][1] = bv;
                acc[rt][gate][2] = bv; acc[rt][gate][3] = bv;
            }
        #pragma unroll
        for (int ks = 0; ks < 4; ++ks) {
            bf16x8 af[4];
            #pragma unroll
            for (int rt = 0; rt < 4; ++rt)
                af[rt] = *(const bf16x8*)(&A[(rt * 16 + ln) * LDA + ks * 32 + g * 8]);
            #pragma unroll
            for (int rt = 0; rt < 4; ++rt)
                #pragma unroll
                for (int gate = 0; gate < 2; ++gate)
                    acc[rt][gate] = __builtin_amdgcn_mfma_f32_16x16x32_bf16(
                        __builtin_bit_cast(bf16x8b, af[rt]),
                        __builtin_bit_cast(bf16x8b, bfrag[gate][ks]),
                        acc[rt][gate], 0, 0, 0);
        }
    };
    // epilogue: D layout col = lane&15 (= n0), row = 4*(lane>>4) + reg
    auto epilogue = [&](int rowbase, f32x4 (&acc)[4][2]) {
        #pragma unroll
        for (int half = 0; half < 2; ++half) {
            #pragma unroll
            for (int qq = 0; qq < 2; ++qq) {
                int rt = half * 2 + qq;
                #pragma unroll
                for (int r = 0; r < 4; ++r) {
                    int rowL = qq * 16 + g * 4 + r;      // 0..31 in this half
                    float cv = acc[rt][0][r];
                    float hv = sigmoid_(acc[rt][1][r]) * tanh_(cv);
                    ce_l[rowL * LDF + n0] = cv;
                    he_l[rowL * LDF + n0] = hv;
                }
            }
            __syncthreads();
            // 32 rows x 192 f32x4 = 6144 units; 12/thread; lanes contiguous
            #pragma unroll
            for (int i = 0; i < 12; ++i) {
                int u  = tid + 512 * i;
                int rg = u / 192;
                int s  = u - rg * 192;      // f32x4 col in row, 0..191
                int sec = s >> 5;           // 0:ce 1:cph 2:cpc 3:he 4:hph 5:hpc
                int cc  = s & 31;
                const float* src =
                    (sec == 0) ? (ce_l + rg * LDF + cc * 4) :
                    (sec == 3) ? (he_l + rg * LDF + cc * 4) :
                    (st_l + ((sec < 3) ? (sec - 1) : (sec - 2)) * 128 + cc * 4);
                f32x4 v = *(const f32x4*)src;
                *(f32x4*)(out + (size_t)(rowbase + half * 32 + rg) * OUTC + s * 4) = v;
            }
            __syncthreads();                // reads done before buffer reuse
        }
    };

    // --- pipeline ----------------------------------------------------------
    f32x4 r0[4], r1[4];
    f32x4 acc[4][2];

    stage_load(rowbase0, r0);
    stage_write(A0, r0);
    __syncthreads();                        // A0 visible

    stage_load(rowbase1, r1);               // t1 reads in flight under t0 work

    do_mfma(A0, acc);
    stage_write(A1, r1);                    // waits vmcnt(r1) here
    __syncthreads();                        // A0 reads done; A1 visible

    epilogue(rowbase0, acc);                // internal barriers order A1 too
    do_mfma(A1, acc);
    epilogue(rowbase1, acc);
}

extern "C" void kernel_launch(void* const* d_in, const int* in_sizes, int n_in,
                              void* d_out, int out_size, void* d_ws, size_t ws_size,
                              hipStream_t stream) {
    const float* embs   = (const float*)d_in[0];
    const float* root_c = (const float*)d_in[1];
    const float* root_h = (const float*)d_in[2];
    const float* Wi = (const float*)d_in[3];
    const float* bi = (const float*)d_in[4];
    const float* Wf = (const float*)d_in[5];
    const float* bfv= (const float*)d_in[6];
    const float* Wu = (const float*)d_in[7];
    const float* bu = (const float*)d_in[8];
    const float* Wc = (const float*)d_in[9];
    const float* bc = (const float*)d_in[10];
    const float* Wo = (const float*)d_in[11];
    const float* bo = (const float*)d_in[12];

    float* out   = (float*)d_out;
    float* state = (float*)d_ws;                       // 128 KB
    short* wbf   = (short*)d_ws + 65536;               // 64 KB bf16 W

    state_kernel<<<dim3(Bb), dim3(512), 0, stream>>>(
        root_c, root_h, Wi, bi, Wf, bfv, Wu, bu, Wc, bc, Wo, bo, state, wbf);
    fused_kernel<<<dim3(1024), dim3(512), 0, stream>>>(
        embs, wbf, bc, bo, state, out);
}